// Round 1
// baseline (3018.860 us; speedup 1.0000x reference)
//
#include <hip/hip_runtime.h>

#define H_ 128
#define T_ 1024
#define B_ 512
#define I_ 13
#define LOG2E 1.4426950408889634f

typedef _Float16 half8 __attribute__((ext_vector_type(8)));
typedef float float4_ __attribute__((ext_vector_type(4)));

static __device__ __forceinline__ float fast_rcp(float v) {
  return __builtin_amdgcn_rcpf(v);
}
static __device__ __forceinline__ float fast_exp2(float v) {
  return __builtin_amdgcn_exp2f(v);
}
static __device__ __forceinline__ float sigmoid_f(float v) {
  return fast_rcp(1.0f + fast_exp2(-LOG2E * v));
}
static __device__ __forceinline__ float tanh_f(float v) {
  return 2.0f * fast_rcp(1.0f + fast_exp2(-2.0f * LOG2E * v)) - 1.0f;
}

// R6: 2 WGs per CU (512 WGs, 1 batch row each) instead of 1 WG / 2 rows.
// The recurrence is latency-bound (~2180 cy/step, ~40% stall at the
// barrier + LDS round-trip + dependent-MFMA chain). Two barrier-decoupled
// WGs per CU drift out of phase and fill each other's stalls.
// Per-WG LDS shrinks to ~65 KB so two fit in 160 KB/CU.
// Per-wave structure (wfrag/af/acc, 124 VGPR) is unchanged from R5;
// only the second A row (n16==4) is dropped.
__global__ __launch_bounds__(512, 4) void lstm_fused(
    const float* __restrict__ x, const float* __restrict__ Wih,
    const float* __restrict__ Whh, const float* __restrict__ bih,
    const float* __restrict__ bhh, const float* __restrict__ Wfc,
    const float* __restrict__ bfc, float* __restrict__ out)
{
  // 32 KB: x(t) for this WG's row (f16), slots 13..15 zero-padded
  __shared__ __align__(16) _Float16 xlds[T_][16];
  // 32 KB: logits ring, slot t holds logits for output row t (cols 0..6)
  __shared__ __align__(16) float lgring[T_][8];
  // 672 B: double-buffered h (cols 0..127 used; stride 168 halfs)
  __shared__ __align__(16) _Float16 abuf[2][168];

  const int tid  = threadIdx.x;
  const int wave = tid >> 6;
  const int lane = tid & 63;
  const int n16  = lane & 15;
  const int quad = lane >> 4;
  const int row  = blockIdx.x;   // this WG's batch row

  // ---- W fragments: wave w owns gate tiles {w, w+8, w+16, w+24} ----
  // B layout (16x16x32): lane holds B[k = quad*8 + j][n = n16]
  half8 wfrag[4][5];
  float biasv[4];
  #pragma unroll
  for (int ti = 0; ti < 4; ++ti) {
    const int col = (wave + 8 * ti) * 16 + n16;
    biasv[ti] = bih[col] + bhh[col];
    #pragma unroll
    for (int kc = 0; kc < 5; ++kc) {
      half8 f;
      #pragma unroll
      for (int j = 0; j < 8; ++j) {
        const int k = kc * 32 + quad * 8 + j;
        float v = 0.0f;
        if (k < 128)            v = Whh[col * H_ + k];
        else if (k < 128 + I_)  v = Wih[col * I_ + (k - 128)];
        f[j] = (_Float16)v;
      }
      wfrag[ti][kc] = f;
    }
  }
  // FC tile (used by wave 6; loaded uniformly), k < 128 -> 4 chunks
  half8 wfc[4];
  const float biasfc = (n16 < 7) ? bfc[n16] : 0.0f;
  #pragma unroll
  for (int kc = 0; kc < 4; ++kc) {
    half8 f;
    #pragma unroll
    for (int j = 0; j < 8; ++j) {
      const int k = kc * 32 + quad * 8 + j;
      f[j] = (_Float16)((n16 < 7) ? Wfc[n16 * H_ + k] : 0.0f);
    }
    wfc[kc] = f;
  }

  // ---- phase 0: preload all x for this row into LDS (f16), zero pads ----
  for (int idx = tid; idx < T_ * 16; idx += 512) {
    const int t  = idx >> 4;
    const int ii = idx & 15;
    float v = 0.0f;
    if (ii < I_) v = x[((size_t)t * B_ + row) * I_ + ii];
    xlds[t][ii] = (_Float16)v;
  }
  for (int idx = tid; idx < 2 * 168; idx += 512)
    ((_Float16*)abuf)[idx] = (_Float16)0.0f;
  __syncthreads();

  float c_state = 0.0f;           // lanes 0..15: cell for col 16*wave+n16
  const bool aload = (n16 == 0);  // A row 0 k-slices live in lanes 0,16,32,48

  half8 af[5];
  {
    half8 z;
    #pragma unroll
    for (int j = 0; j < 8; ++j) z[j] = (_Float16)0.0f;
    #pragma unroll
    for (int kc = 0; kc < 5; ++kc) af[kc] = z;
  }

  float4_ acc[4];
  #pragma unroll
  for (int ti = 0; ti < 4; ++ti)
    #pragma unroll
    for (int r = 0; r < 4; ++r) acc[ti][r] = 0.0f;
  float4_ accf;
  #pragma unroll
  for (int r = 0; r < 4; ++r) accf[r] = 0.0f;

  // ---- phase 1: the recurrence. No vector-memory ops in this loop. ----
  for (int t = 0; t <= T_; ++t) {
    // A fragments: h chunks 0..3 from abuf, x chunk 4 from xlds[t]
    if (aload) {
      #pragma unroll
      for (int kc = 0; kc < 4; ++kc)
        af[kc] = *(const half8*)&abuf[t & 1][kc * 32 + quad * 8];
      if (quad < 2 && t < T_)
        af[4] = *(const half8*)&xlds[t][quad * 8];
    }

    if (t < T_) {
      #pragma unroll
      for (int ti = 0; ti < 4; ++ti) acc[ti][0] = biasv[ti];
      #pragma unroll
      for (int kc = 0; kc < 5; ++kc) {
        #pragma unroll
        for (int ti = 0; ti < 4; ++ti)
          acc[ti] = __builtin_amdgcn_mfma_f32_16x16x32_f16(af[kc], wfrag[ti][kc], acc[ti], 0, 0, 0);
      }
      // cell update from accumulators (D row 0 = lanes 0..15, reg 0)
      if (lane < 16) {
        const float iv = sigmoid_f(acc[0][0]);
        const float fv = sigmoid_f(acc[1][0]);
        const float gv = tanh_f(acc[2][0]);
        const float ov = sigmoid_f(acc[3][0]);
        c_state = fv * c_state + iv * gv;
        const float hv = ov * tanh_f(c_state);
        abuf[(t + 1) & 1][16 * wave + n16] = (_Float16)hv;
      }
    }

    // FC logits: af holds h_{t-1} here -> logits for output row t-1
    if (wave == 6 && t >= 1) {
      accf[0] = biasfc;
      #pragma unroll
      for (int kc = 0; kc < 4; ++kc)
        accf = __builtin_amdgcn_mfma_f32_16x16x32_f16(af[kc], wfc[kc], accf, 0, 0, 0);
      if (lane < 7)
        lgring[t - 1][n16] = accf[0];
    }

    __syncthreads();
  }

  // ---- phase 2: softmax of this row's T_ logit rows -> out ----
  for (int r = tid; r < T_; r += 512) {
    float lg[7];
    float mx = -3.0e38f;
    #pragma unroll
    for (int k = 0; k < 7; ++k) {
      lg[k] = lgring[r][k];
      mx = fmaxf(mx, lg[k]);
    }
    float s = 0.0f;
    #pragma unroll
    for (int k = 0; k < 7; ++k) {
      lg[k] = fast_exp2(LOG2E * (lg[k] - mx));
      s += lg[k];
    }
    const float rs = fast_rcp(s);
    float* op = &out[((size_t)r * B_ + row) * 7];
    #pragma unroll
    for (int k = 0; k < 7; ++k) op[k] = lg[k] * rs;
  }
}

extern "C" void kernel_launch(void* const* d_in, const int* in_sizes, int n_in,
                              void* d_out, int out_size, void* d_ws, size_t ws_size,
                              hipStream_t stream) {
  (void)in_sizes; (void)n_in; (void)out_size; (void)d_ws; (void)ws_size;
  const float* x   = (const float*)d_in[0];
  const float* Wih = (const float*)d_in[1];
  const float* Whh = (const float*)d_in[2];
  const float* bih = (const float*)d_in[3];
  const float* bhh = (const float*)d_in[4];
  const float* Wfc = (const float*)d_in[5];
  const float* bfc = (const float*)d_in[6];
  hipLaunchKernelGGL(lstm_fused, dim3(512), dim3(512), 0, stream,
                     x, Wih, Whh, bih, bhh, Wfc, bfc, (float*)d_out);
}

// Round 2
// 1953.195 us; speedup vs baseline: 1.5456x; 1.5456x over previous
//
#include <hip/hip_runtime.h>

#define H_ 128
#define T_ 1024
#define B_ 512
#define I_ 13
#define LOG2E 1.4426950408889634f

typedef _Float16 half8 __attribute__((ext_vector_type(8)));
typedef float float4_ __attribute__((ext_vector_type(4)));

static __device__ __forceinline__ float fast_rcp(float v) {
  return __builtin_amdgcn_rcpf(v);
}
static __device__ __forceinline__ float fast_exp2(float v) {
  return __builtin_amdgcn_exp2f(v);
}
static __device__ __forceinline__ float sigmoid_f(float v) {
  return fast_rcp(1.0f + fast_exp2(-LOG2E * v));
}
static __device__ __forceinline__ float tanh_f(float v) {
  return 2.0f * fast_rcp(1.0f + fast_exp2(-2.0f * LOG2E * v)) - 1.0f;
}

// R7: fix R6's register-cap disaster.
// R6 evidence: __launch_bounds__(512,4) => VGPR_Count=64 (the 2nd arg acts
// as blocks/CU: 4 blk * 8 waves = 8 waves/SIMD -> 512/8 = 64 cap), which
// spilled the 80-VGPR wfrag to scratch (FETCH 117MB / WRITE 182MB).
// Occupancy DID reach 47% (2 WGs/CU co-resident), so keep the structure:
//   512 WGs, 1 batch row each, 2 WGs/CU overlapping each other's stalls.
// Changes vs R6:
//   - __launch_bounds__(512, 2): 2 blk/CU * 8 waves = 4 waves/SIMD -> 128 cap.
//   - wfc moved to LDS (saves 16 loop-long VGPRs in every wave; volatile
//     reads in wave 6 so LICM can't hoist them back into registers).
__global__ __launch_bounds__(512, 2) void lstm_fused(
    const float* __restrict__ x, const float* __restrict__ Wih,
    const float* __restrict__ Whh, const float* __restrict__ bih,
    const float* __restrict__ bhh, const float* __restrict__ Wfc,
    const float* __restrict__ bfc, float* __restrict__ out)
{
  // 32 KB: x(t) for this WG's row (f16), slots 13..15 zero-padded
  __shared__ __align__(16) _Float16 xlds[T_][16];
  // 32 KB: logits ring, slot t holds logits for output row t (cols 0..6)
  __shared__ __align__(16) float lgring[T_][8];
  // 672 B: double-buffered h (cols 0..127 used; stride 168 halfs)
  __shared__ __align__(16) _Float16 abuf[2][168];
  // 4 KB: FC weight fragments, wfc_lds[kc][lane] = half8
  __shared__ __align__(16) half8 wfc_lds[4][64];

  const int tid  = threadIdx.x;
  const int wave = tid >> 6;
  const int lane = tid & 63;
  const int n16  = lane & 15;
  const int quad = lane >> 4;
  const int row  = blockIdx.x;   // this WG's batch row

  // ---- W fragments: wave w owns gate tiles {w, w+8, w+16, w+24} ----
  // B layout (16x16x32): lane holds B[k = quad*8 + j][n = n16]
  half8 wfrag[4][5];
  float biasv[4];
  #pragma unroll
  for (int ti = 0; ti < 4; ++ti) {
    const int col = (wave + 8 * ti) * 16 + n16;
    biasv[ti] = bih[col] + bhh[col];
    #pragma unroll
    for (int kc = 0; kc < 5; ++kc) {
      half8 f;
      #pragma unroll
      for (int j = 0; j < 8; ++j) {
        const int k = kc * 32 + quad * 8 + j;
        float v = 0.0f;
        if (k < 128)            v = Whh[col * H_ + k];
        else if (k < 128 + I_)  v = Wih[col * I_ + (k - 128)];
        f[j] = (_Float16)v;
      }
      wfrag[ti][kc] = f;
    }
  }
  // FC tile -> LDS (only wave 6 consumes it in the loop)
  const float biasfc = (n16 < 7) ? bfc[n16] : 0.0f;
  if (wave == 6) {
    #pragma unroll
    for (int kc = 0; kc < 4; ++kc) {
      half8 f;
      #pragma unroll
      for (int j = 0; j < 8; ++j) {
        const int k = kc * 32 + quad * 8 + j;
        f[j] = (_Float16)((n16 < 7) ? Wfc[n16 * H_ + k] : 0.0f);
      }
      wfc_lds[kc][lane] = f;
    }
  }

  // ---- phase 0: preload all x for this row into LDS (f16), zero pads ----
  for (int idx = tid; idx < T_ * 16; idx += 512) {
    const int t  = idx >> 4;
    const int ii = idx & 15;
    float v = 0.0f;
    if (ii < I_) v = x[((size_t)t * B_ + row) * I_ + ii];
    xlds[t][ii] = (_Float16)v;
  }
  for (int idx = tid; idx < 2 * 168; idx += 512)
    ((_Float16*)abuf)[idx] = (_Float16)0.0f;
  __syncthreads();

  float c_state = 0.0f;           // lanes 0..15: cell for col 16*wave+n16
  const bool aload = (n16 == 0);  // A row 0 k-slices live in lanes 0,16,32,48

  half8 af[5];
  {
    half8 z;
    #pragma unroll
    for (int j = 0; j < 8; ++j) z[j] = (_Float16)0.0f;
    #pragma unroll
    for (int kc = 0; kc < 5; ++kc) af[kc] = z;
  }

  float4_ acc[4];
  #pragma unroll
  for (int ti = 0; ti < 4; ++ti)
    #pragma unroll
    for (int r = 0; r < 4; ++r) acc[ti][r] = 0.0f;
  float4_ accf;
  #pragma unroll
  for (int r = 0; r < 4; ++r) accf[r] = 0.0f;

  // ---- phase 1: the recurrence. No vector-memory ops in this loop. ----
  for (int t = 0; t <= T_; ++t) {
    // A fragments: h chunks 0..3 from abuf, x chunk 4 from xlds[t]
    if (aload) {
      #pragma unroll
      for (int kc = 0; kc < 4; ++kc)
        af[kc] = *(const half8*)&abuf[t & 1][kc * 32 + quad * 8];
      if (quad < 2 && t < T_)
        af[4] = *(const half8*)&xlds[t][quad * 8];
    }

    if (t < T_) {
      #pragma unroll
      for (int ti = 0; ti < 4; ++ti) acc[ti][0] = biasv[ti];
      #pragma unroll
      for (int kc = 0; kc < 5; ++kc) {
        #pragma unroll
        for (int ti = 0; ti < 4; ++ti)
          acc[ti] = __builtin_amdgcn_mfma_f32_16x16x32_f16(af[kc], wfrag[ti][kc], acc[ti], 0, 0, 0);
      }
      // cell update from accumulators (D row 0 = lanes 0..15, reg 0)
      if (lane < 16) {
        const float iv = sigmoid_f(acc[0][0]);
        const float fv = sigmoid_f(acc[1][0]);
        const float gv = tanh_f(acc[2][0]);
        const float ov = sigmoid_f(acc[3][0]);
        c_state = fv * c_state + iv * gv;
        const float hv = ov * tanh_f(c_state);
        abuf[(t + 1) & 1][16 * wave + n16] = (_Float16)hv;
      }
    }

    // FC logits: af holds h_{t-1} here -> logits for output row t-1.
    // wfc read back from LDS each step (volatile: keep it out of VGPRs).
    if (wave == 6 && t >= 1) {
      accf[0] = biasfc;
      #pragma unroll
      for (int kc = 0; kc < 4; ++kc) {
        const half8 wf = *(const volatile half8*)&wfc_lds[kc][lane];
        accf = __builtin_amdgcn_mfma_f32_16x16x32_f16(af[kc], wf, accf, 0, 0, 0);
      }
      if (lane < 7)
        lgring[t - 1][n16] = accf[0];
    }

    __syncthreads();
  }

  // ---- phase 2: softmax of this row's T_ logit rows -> out ----
  for (int r = tid; r < T_; r += 512) {
    float lg[7];
    float mx = -3.0e38f;
    #pragma unroll
    for (int k = 0; k < 7; ++k) {
      lg[k] = lgring[r][k];
      mx = fmaxf(mx, lg[k]);
    }
    float s = 0.0f;
    #pragma unroll
    for (int k = 0; k < 7; ++k) {
      lg[k] = fast_exp2(LOG2E * (lg[k] - mx));
      s += lg[k];
    }
    const float rs = fast_rcp(s);
    float* op = &out[((size_t)r * B_ + row) * 7];
    #pragma unroll
    for (int k = 0; k < 7; ++k) op[k] = lg[k] * rs;
  }
}

extern "C" void kernel_launch(void* const* d_in, const int* in_sizes, int n_in,
                              void* d_out, int out_size, void* d_ws, size_t ws_size,
                              hipStream_t stream) {
  (void)in_sizes; (void)n_in; (void)out_size; (void)d_ws; (void)ws_size;
  const float* x   = (const float*)d_in[0];
  const float* Wih = (const float*)d_in[1];
  const float* Whh = (const float*)d_in[2];
  const float* bih = (const float*)d_in[3];
  const float* bhh = (const float*)d_in[4];
  const float* Wfc = (const float*)d_in[5];
  const float* bfc = (const float*)d_in[6];
  hipLaunchKernelGGL(lstm_fused, dim3(512), dim3(512), 0, stream,
                     x, Wih, Whh, bih, bhh, Wfc, bfc, (float*)d_out);
}

// Round 3
// 932.320 us; speedup vs baseline: 3.2380x; 2.0950x over previous
//
#include <hip/hip_runtime.h>

#define H_ 128
#define T_ 1024
#define B_ 512
#define I_ 13
#define LOG2E 1.4426950408889634f

typedef _Float16 half8 __attribute__((ext_vector_type(8)));
typedef float float4_ __attribute__((ext_vector_type(4)));

static __device__ __forceinline__ float fast_rcp(float v) {
  return __builtin_amdgcn_rcpf(v);
}
static __device__ __forceinline__ float fast_exp2(float v) {
  return __builtin_amdgcn_exp2f(v);
}
static __device__ __forceinline__ float sigmoid_f(float v) {
  return fast_rcp(1.0f + fast_exp2(-LOG2E * v));
}
static __device__ __forceinline__ float tanh_f(float v) {
  return 2.0f * fast_rcp(1.0f + fast_exp2(-2.0f * LOG2E * v)) - 1.0f;
}

// R8: 4-wave WG (256 thr), 2 rows, 256 WGs, 1 wave/SIMD.
// Rationale: time = 1024 * step-period and B/CU is fixed, so the only
// lever is the period (R5: ~2200 cy vs ~800 cy intrinsic chain).
// vs R5 (8 waves): each wave owns 8 gate tiles (all 4 gates for two
// 16-col groups) -> 8 independent 5-deep MFMA chains per wave (vs 4),
// one full-wave activation pass via 4 shuffles (vs 8 masked passes/CU),
// x-fragment prefetched a step early, 4-wave barrier with no SIMD pairing.
// Per-SIMD MFMA/VALU totals unchanged; only serialization structure changes.
// 1 wave/SIMD => VGPR budget 512; wfrag(160)+acc(32)+af(24)+wfc(16) fits.
__global__ __launch_bounds__(256, 1) void lstm_fused(
    const float* __restrict__ x, const float* __restrict__ Wih,
    const float* __restrict__ Whh, const float* __restrict__ bih,
    const float* __restrict__ bhh, const float* __restrict__ Wfc,
    const float* __restrict__ bfc, float* __restrict__ out)
{
  // 64 KB: x(t) for both rows (f16), slots 13..15 zero (pad to k-chunk)
  __shared__ __align__(16) _Float16 xlds[T_][2][16];
  // 64 KB: logits ring, slot t holds logits for output row t (cols 0..6)
  __shared__ __align__(16) float lgring[T_][2][8];
  // 1.3 KB: double-buffered h (cols 0..127 used; stride 168 halfs)
  __shared__ __align__(16) _Float16 abuf[2][2][168];

  const int tid  = threadIdx.x;
  const int wave = tid >> 6;      // 0..3
  const int lane = tid & 63;
  const int n16  = lane & 15;
  const int quad = lane >> 4;
  const int wgb  = blockIdx.x * 2;

  // ---- W fragments: wave w owns tiles {g*8 + 2w + p : g=0..3, p=0..1} ----
  // (all 4 gates for col-groups 2w and 2w+1 -> cell update is wave-local)
  // B layout (16x16x32): lane holds B[k = quad*8 + j][n = n16]
  half8 wfrag[8][5];
  float biasv[8];
  #pragma unroll
  for (int ti = 0; ti < 8; ++ti) {
    const int g    = ti >> 1;
    const int p    = ti & 1;
    const int tile = g * 8 + 2 * wave + p;
    const int col  = tile * 16 + n16;
    biasv[ti] = bih[col] + bhh[col];
    #pragma unroll
    for (int kc = 0; kc < 5; ++kc) {
      half8 f;
      #pragma unroll
      for (int j = 0; j < 8; ++j) {
        const int k = kc * 32 + quad * 8 + j;
        float v = 0.0f;
        if (k < 128)            v = Whh[col * H_ + k];
        else if (k < 128 + I_)  v = Wih[col * I_ + (k - 128)];
        f[j] = (_Float16)v;
      }
      wfrag[ti][kc] = f;
    }
  }
  // FC tile (consumed by wave 3; loaded uniformly), k < 128 -> 4 chunks
  half8 wfc[4];
  const float biasfc = (n16 < 7) ? bfc[n16] : 0.0f;
  #pragma unroll
  for (int kc = 0; kc < 4; ++kc) {
    half8 f;
    #pragma unroll
    for (int j = 0; j < 8; ++j) {
      const int k = kc * 32 + quad * 8 + j;
      f[j] = (_Float16)((n16 < 7) ? Wfc[n16 * H_ + k] : 0.0f);
    }
    wfc[kc] = f;
  }

  // ---- phase 0: preload all x for this WG into LDS (f16), zero pads ----
  for (int idx = tid; idx < T_ * 2 * 16; idx += 256) {
    const int t  = idx >> 5;
    const int rw = (idx >> 4) & 1;
    const int ii = idx & 15;
    float v = 0.0f;
    if (ii < I_) v = x[((size_t)t * B_ + wgb + rw) * I_ + ii];
    xlds[t][rw][ii] = (_Float16)v;
  }
  for (int idx = tid; idx < 2 * 2 * 168; idx += 256)
    ((_Float16*)abuf)[idx] = (_Float16)0.0f;
  __syncthreads();

  // cell state: full wave. lane -> (row=(lane>>4)&1, col=32w+(lane>=32?16:0)+n16)
  float c_state = 0.0f;
  const int  hrow = (lane >> 4) & 1;
  const int  hcol = 32 * wave + ((lane >= 32) ? 16 : 0) + n16;
  const bool aload = (n16 == 0) || (n16 == 4);  // A rows 0 and 4
  const int  arow  = n16 >> 2;

  half8 af[4];
  half8 af4;
  {
    half8 z;
    #pragma unroll
    for (int j = 0; j < 8; ++j) z[j] = (_Float16)0.0f;
    #pragma unroll
    for (int kc = 0; kc < 4; ++kc) af[kc] = z;
    af4 = z;
  }
  // preload x fragment for t=0 (xlds is static; prefetched ahead in-loop)
  if (aload && quad < 2)
    af4 = *(const half8*)&xlds[0][arow][quad * 8];

  float4_ acc[8];
  #pragma unroll
  for (int ti = 0; ti < 8; ++ti)
    #pragma unroll
    for (int r = 0; r < 4; ++r) acc[ti][r] = 0.0f;
  float4_ accf;
  #pragma unroll
  for (int r = 0; r < 4; ++r) accf[r] = 0.0f;

  // ---- phase 1: the recurrence. No vector-memory ops in this loop. ----
  for (int t = 0; t <= T_; ++t) {
    // A fragments: h chunks 0..3 from abuf (x chunk af4 prefetched)
    if (aload) {
      #pragma unroll
      for (int kc = 0; kc < 4; ++kc)
        af[kc] = *(const half8*)&abuf[t & 1][arow][kc * 32 + quad * 8];
    }

    if (t < T_) {
      #pragma unroll
      for (int ti = 0; ti < 8; ++ti) acc[ti][0] = biasv[ti];
      // 8 independent 5-deep chains: kc outer, ti inner keeps the MFMA
      // pipe fed from a single in-order wave.
      #pragma unroll
      for (int kc = 0; kc < 4; ++kc) {
        #pragma unroll
        for (int ti = 0; ti < 8; ++ti)
          acc[ti] = __builtin_amdgcn_mfma_f32_16x16x32_f16(af[kc], wfrag[ti][kc], acc[ti], 0, 0, 0);
      }
      #pragma unroll
      for (int ti = 0; ti < 8; ++ti)
        acc[ti] = __builtin_amdgcn_mfma_f32_16x16x32_f16(af4, wfrag[ti][4], acc[ti], 0, 0, 0);

      // prefetch next x fragment (independent of everything below)
      if (aload && quad < 2 && t + 1 < T_)
        af4 = *(const half8*)&xlds[t + 1][arow][quad * 8];

      // cell update, FULL wave: lanes<32 take pair p=0 (cols 32w..+15),
      // lanes>=32 take pair p=1 (cols 32w+16..+31) fetched via shuffle.
      float gv[4];
      #pragma unroll
      for (int g = 0; g < 4; ++g) {
        const float vB = __shfl(acc[2 * g + 1][0], lane & 31);
        gv[g] = (lane < 32) ? acc[2 * g][0] : vB;
      }
      const float iv = sigmoid_f(gv[0]);
      const float fv = sigmoid_f(gv[1]);
      const float gg = tanh_f(gv[2]);
      const float ov = sigmoid_f(gv[3]);
      c_state = fv * c_state + iv * gg;
      const float hv = ov * tanh_f(c_state);
      abuf[(t + 1) & 1][hrow][hcol] = (_Float16)hv;
    }

    // FC logits: af holds h_t here -> logits for output row t-1
    if (wave == 3 && t >= 1) {
      accf[0] = biasfc;
      #pragma unroll
      for (int kc = 0; kc < 4; ++kc)
        accf = __builtin_amdgcn_mfma_f32_16x16x32_f16(af[kc], wfc[kc], accf, 0, 0, 0);
      if (lane < 32 && n16 < 7)
        lgring[t - 1][quad][n16] = accf[0];
    }

    __syncthreads();
  }

  // ---- phase 2: softmax of all 2048 logit rows -> out ----
  for (int r = tid; r < T_ * 2; r += 256) {
    const int t = r >> 1;
    const int b = r & 1;
    float lg[7];
    float mx = -3.0e38f;
    #pragma unroll
    for (int k = 0; k < 7; ++k) {
      lg[k] = lgring[t][b][k];
      mx = fmaxf(mx, lg[k]);
    }
    float s = 0.0f;
    #pragma unroll
    for (int k = 0; k < 7; ++k) {
      lg[k] = fast_exp2(LOG2E * (lg[k] - mx));
      s += lg[k];
    }
    const float rs = fast_rcp(s);
    float* op = &out[((size_t)t * B_ + wgb + b) * 7];
    #pragma unroll
    for (int k = 0; k < 7; ++k) op[k] = lg[k] * rs;
  }
}

extern "C" void kernel_launch(void* const* d_in, const int* in_sizes, int n_in,
                              void* d_out, int out_size, void* d_ws, size_t ws_size,
                              hipStream_t stream) {
  (void)in_sizes; (void)n_in; (void)out_size; (void)d_ws; (void)ws_size;
  const float* x   = (const float*)d_in[0];
  const float* Wih = (const float*)d_in[1];
  const float* Whh = (const float*)d_in[2];
  const float* bih = (const float*)d_in[3];
  const float* bhh = (const float*)d_in[4];
  const float* Wfc = (const float*)d_in[5];
  const float* bfc = (const float*)d_in[6];
  hipLaunchKernelGGL(lstm_fused, dim3(256), dim3(256), 0, stream,
                     x, Wih, Whh, bih, bhh, Wfc, bfc, (float*)d_out);
}